// Round 2
// baseline (272.736 us; speedup 1.0000x reference)
//
#include <hip/hip_runtime.h>
#include <math.h>

#define E_TOTAL 20000
#define G 8            // edges per block
#define BLK 384        // threads (6 waves)
#define NB 64          // num basis
#define HID 128
#define MULD 1536      // 6*16*16

typedef float f32x4 __attribute__((ext_vector_type(4)));

__global__ __launch_bounds__(BLK) void fused_tp_kernel(
    const float* __restrict__ r,      // [E,3]
    const float* __restrict__ W1,     // [64,128]
    const float* __restrict__ b1,     // [128]
    const float* __restrict__ W2,     // [128,1536]
    const float* __restrict__ b2,     // [1536]
    const float* __restrict__ wl0,    // [16,16]
    const float* __restrict__ wl1,    // [16,16]
    float* __restrict__ out)          // [E,64,64]
{
    __shared__ __align__(16) float s_basis[G][NB];
    __shared__ __align__(16) float s_h[HID][G];     // transposed: [k][g]
    __shared__ __align__(16) float s_Rw[G][MULD];
    __shared__ float s_Y1[G][3];
    __shared__ float s_A1[G][9];   // n1 * (eps . Y1)/sqrt6
    __shared__ float s_A2[G][9];   // n1 * (T112 . Y2)
    __shared__ float s_rad[G];
    __shared__ int   s_mask[G];

    const int t  = threadIdx.x;
    const int e0 = blockIdx.x * G;

    // ---------------- Phase A: per-edge geometry ----------------
    if (t < G) {
        const int e = e0 + t;
        float rx = r[e*3+0], ry = r[e*3+1], rz = r[e*3+2];
        float rad = sqrtf(rx*rx + ry*ry + rz*rz);
        s_rad[t]  = rad;
        s_mask[t] = (rad > 0.0f) ? 1 : 0;
        float inv = 1.0f / fmaxf(rad, 1e-12f);
        float x = rx*inv, y = ry*inv, z = rz*inv;

        const float SQ3  = 1.7320508075688772f;
        const float SQ15 = 3.872983346207417f;
        float Y10 = SQ3*y, Y11 = SQ3*z, Y12 = SQ3*x;   // e3nn order (y,z,x)
        s_Y1[t][0]=Y10; s_Y1[t][1]=Y11; s_Y1[t][2]=Y12;

        float Y20 = SQ15*x*y;
        float Y21 = SQ15*y*z;
        float Y22 = 1.118033988749895f*(3.f*z*z - 1.f);   // sqrt(5)/2
        float Y23 = SQ15*z*x;
        float Y24 = 1.9364916731037085f*(x*x - y*y);      // sqrt(15)/2

        const float n1  = 0.21650635094610965f;  // sqrt(3)/8
        const float r6  = 0.4082482904638631f;   // 1/sqrt(6)
        const float cA1 = n1 * r6;
        // A1n[a][b] = n1/sqrt6 * sum_f eps[a,b,f] Y1[f]
        s_A1[t][0] = 0.0f;      s_A1[t][1] =  cA1*Y12; s_A1[t][2] = -cA1*Y11;
        s_A1[t][3] = -cA1*Y12;  s_A1[t][4] = 0.0f;     s_A1[t][5] =  cA1*Y10;
        s_A1[t][6] =  cA1*Y11;  s_A1[t][7] = -cA1*Y10; s_A1[t][8] = 0.0f;

        // M[p][q] = sum_f B[p][q][f] * Y2[f]  (symmetric)
        const float s2 = 0.7071067811865476f;
        float M00 = -r6*Y22 + s2*Y24;
        float M01 =  s2*Y20;
        float M02 =  s2*Y23;
        float M11 = -r6*Y22 - s2*Y24;
        float M12 =  s2*Y21;
        float M22 =  2.0f*r6*Y22;
        // A2n[a][b] = n1 * M[perm[a]][perm[b]] / sqrt5,  perm = [1,2,0]
        const float c5 = n1 * 0.4472135954999579f;  // n1/sqrt(5)
        s_A2[t][0] = c5*M11; s_A2[t][1] = c5*M12; s_A2[t][2] = c5*M01;
        s_A2[t][3] = c5*M12; s_A2[t][4] = c5*M22; s_A2[t][5] = c5*M02;
        s_A2[t][6] = c5*M01; s_A2[t][7] = c5*M02; s_A2[t][8] = c5*M00;
    }
    __syncthreads();

    // ---------------- Phase B: RBF basis ----------------
    for (int idx = t; idx < G*NB; idx += BLK) {
        int g = idx >> 6, k = idx & 63;
        float rad = s_rad[g];
        float c = (3.0f * (float)k) * (1.0f/63.0f);
        float d = (rad - c) * (64.0f/3.0f);
        s_basis[g][k] = __expf(-d*d);
    }
    __syncthreads();

    // ---------------- Phase C: h = silu(basis @ W1 + b1), stored [k][g] ----------------
    for (int idx = t; idx < G*HID; idx += BLK) {
        int g = idx >> 7, c = idx & 127;
        float acc = b1[c];
#pragma unroll 8
        for (int k = 0; k < NB; ++k)
            acc = fmaf(s_basis[g][k], W1[k*HID + c], acc);
        float sig = 1.0f / (1.0f + __expf(-acc));
        s_h[c][g] = acc * sig;
    }
    __syncthreads();

    // ---------------- Phase D: Rw = h @ W2 + b2 ----------------
    // thread t owns cols [4t, 4t+4) for all G edges (t < 384 covers 1536 exactly)
    {
        const int n0 = t * 4;
        float4 acc[G];
        const float4 bb = *reinterpret_cast<const float4*>(&b2[n0]);
#pragma unroll
        for (int g = 0; g < G; ++g) acc[g] = bb;

        const float* w2p = &W2[n0];
#pragma unroll 4
        for (int k = 0; k < HID; ++k) {
            const float4 w  = *reinterpret_cast<const float4*>(&w2p[(size_t)k * MULD]);
            const float4 hA = *reinterpret_cast<const float4*>(&s_h[k][0]);
            const float4 hB = *reinterpret_cast<const float4*>(&s_h[k][4]);
            const float hv[8] = {hA.x, hA.y, hA.z, hA.w, hB.x, hB.y, hB.z, hB.w};
#pragma unroll
            for (int g = 0; g < G; ++g) {
                acc[g].x = fmaf(hv[g], w.x, acc[g].x);
                acc[g].y = fmaf(hv[g], w.y, acc[g].y);
                acc[g].z = fmaf(hv[g], w.z, acc[g].z);
                acc[g].w = fmaf(hv[g], w.w, acc[g].w);
            }
        }
#pragma unroll
        for (int g = 0; g < G; ++g)
            *reinterpret_cast<float4*>(&s_Rw[g][n0]) = acc[g];
    }
    __syncthreads();

    // ---------------- Phase E: assemble 64x64 kernel per edge, float4 stores ----------------
    const float c00 = 0.17677669529663687f;   // 1/sqrt(32)
    const float cTR = 0.10206207261596577f;   // 1/sqrt(32)/sqrt(3)
    const float cBL = 0.125f;                 // (sqrt3/8)/sqrt3
    const float cD  = 0.125f;                 // n1/sqrt3 (diag term of path (1,1,0))

    for (int c = t; c < G*1024; c += BLK) {
        const int g   = c >> 10;
        const int idx = (c & 1023) * 4;   // element index within 64x64
        const int row = idx >> 6;
        const int col = idx & 63;
        const float* Rw = s_Rw[g];
        float v[4];

        if (!s_mask[g]) {
            // masked-out edge: constant kernel2
#pragma unroll
            for (int j = 0; j < 4; ++j) {
                int cl = col + j;
                float val = 0.0f;
                if (row < 16 && cl < 16) {
                    val = wl0[row*16 + cl] * 0.25f;
                } else if (row >= 16 && cl >= 16) {
                    int o = (row-16)/3, a = (row-16)%3;
                    int i = (cl-16)/3,  b = (cl-16)%3;
                    val = (a == b) ? wl1[o*16 + i] * 0.25f : 0.0f;
                }
                v[j] = val;
            }
        } else if (row < 16) {
            if (col < 16) {
                // path (0,0,0)
#pragma unroll
                for (int j = 0; j < 4; ++j)
                    v[j] = c00 * Rw[0*256 + row*16 + col + j];
            } else {
                // path (1,0,1): col = 16 + i*3 + b
#pragma unroll
                for (int j = 0; j < 4; ++j) {
                    int cc = col + j - 16;
                    int i = cc / 3, b = cc % 3;
                    v[j] = cTR * Rw[2*256 + row*16 + i] * s_Y1[g][b];
                }
            }
        } else {
            const int o = (row-16)/3, a = (row-16)%3;
            if (col < 16) {
                // path (0,1,1): row = 16 + o*3 + a
                const float ya = cBL * s_Y1[g][a];
#pragma unroll
                for (int j = 0; j < 4; ++j)
                    v[j] = ya * Rw[1*256 + o*16 + col + j];
            } else {
                // paths (1,1,0)+(1,1,1)+(1,1,2)
#pragma unroll
                for (int j = 0; j < 4; ++j) {
                    int cc = col + j - 16;
                    int i = cc / 3, b = cc % 3;
                    float rv3 = Rw[3*256 + o*16 + i];
                    float rv4 = Rw[4*256 + o*16 + i];
                    float rv5 = Rw[5*256 + o*16 + i];
                    float val = rv4 * s_A1[g][a*3+b] + rv5 * s_A2[g][a*3+b];
                    if (a == b) val = fmaf(rv3, cD, val);
                    v[j] = val;
                }
            }
        }
        const size_t e = (size_t)(e0 + g);
        f32x4 pack = {v[0], v[1], v[2], v[3]};
        __builtin_nontemporal_store(pack, reinterpret_cast<f32x4*>(&out[e*4096 + (size_t)idx]));
    }
}

extern "C" void kernel_launch(void* const* d_in, const int* in_sizes, int n_in,
                              void* d_out, int out_size, void* d_ws, size_t ws_size,
                              hipStream_t stream) {
    const float* r   = (const float*)d_in[0];
    const float* W1  = (const float*)d_in[1];
    const float* b1  = (const float*)d_in[2];
    const float* W2  = (const float*)d_in[3];
    const float* b2  = (const float*)d_in[4];
    const float* wl0 = (const float*)d_in[5];
    const float* wl1 = (const float*)d_in[6];
    float* out = (float*)d_out;

    const int nblocks = E_TOTAL / G;   // 20000/8 = 2500 exactly
    fused_tp_kernel<<<nblocks, BLK, 0, stream>>>(r, W1, b1, W2, b2, wl0, wl1, out);
}

// Round 3
// 220.710 us; speedup vs baseline: 1.2357x; 1.2357x over previous
//
#include <hip/hip_runtime.h>
#include <math.h>

#define E_TOTAL 20000
#define G 16           // edges per block
#define BLK 384        // 6 waves, one per path
#define NB 64
#define HID 128
#define MULD 1536

typedef float f32x4 __attribute__((ext_vector_type(4)));
typedef short bf16x8 __attribute__((ext_vector_type(8)));

static __device__ __forceinline__ unsigned short f2bf(float f) {
    unsigned int u = __float_as_uint(f);
    unsigned int r = u + 0x7FFFu + ((u >> 16) & 1u);
    return (unsigned short)(r >> 16);
}
static __device__ __forceinline__ float bf2f(unsigned short h) {
    return __uint_as_float(((unsigned int)h) << 16);
}

// ---------------- prep: W2 [128][1536] fp32 -> W2t hi/lo [1536][128] bf16 ----------------
__global__ __launch_bounds__(256) void prep_w2(const float* __restrict__ W2,
                                               unsigned short* __restrict__ hi,
                                               unsigned short* __restrict__ lo) {
    __shared__ float s[32][132];
    const int n0 = blockIdx.x * 32;
    const int t = threadIdx.x;
    for (int rep = 0; rep < 16; ++rep) {
        int idx = rep * 256 + t;         // 4096 = 128k x 32n
        int k = idx >> 5, c = idx & 31;
        s[c][k] = W2[k * MULD + n0 + c];
    }
    __syncthreads();
    const int nl = t >> 3, kq = t & 7;
    unsigned short hb[16], lb[16];
#pragma unroll
    for (int j = 0; j < 16; ++j) {
        float f = s[nl][kq * 16 + j];
        unsigned short h = f2bf(f);
        float rem = f - bf2f(h);
        hb[j] = h;
        lb[j] = f2bf(rem);
    }
    const size_t base = (size_t)(n0 + nl) * 128 + kq * 16;
    *reinterpret_cast<uint4*>(&hi[base])     = *reinterpret_cast<uint4*>(&hb[0]);
    *reinterpret_cast<uint4*>(&hi[base + 8]) = *reinterpret_cast<uint4*>(&hb[8]);
    *reinterpret_cast<uint4*>(&lo[base])     = *reinterpret_cast<uint4*>(&lb[0]);
    *reinterpret_cast<uint4*>(&lo[base + 8]) = *reinterpret_cast<uint4*>(&lb[8]);
}

// ---------------- main fused kernel ----------------
__global__ __launch_bounds__(BLK, 3) void fused_tp_kernel(
    const float* __restrict__ r,
    const float* __restrict__ W1,
    const float* __restrict__ b1,
    const unsigned short* __restrict__ w2hi,  // [1536][128] bf16 hi
    const unsigned short* __restrict__ w2lo,  // [1536][128] bf16 lo
    const float* __restrict__ b2,
    const float* __restrict__ wl0,
    const float* __restrict__ wl1,
    float* __restrict__ out)
{
    __shared__ __align__(16) float s_h[G][132];     // h fp32, padded
    __shared__ __align__(16) float s_basis[G][NB];
    __shared__ __align__(16) float s_rv[3][G][260]; // paths 3,4,5 Rw slices, padded
    __shared__ float s_Y1[G][3];
    __shared__ float s_A1[G][9];
    __shared__ float s_A2[G][9];
    __shared__ float s_rad[G];
    __shared__ int   s_mask[G];

    const int t  = threadIdx.x;
    const int e0 = blockIdx.x * G;
    const int w  = t >> 6;        // wave id = path id
    const int l  = t & 63;
    const int lr = l & 15;        // n-col within tile / h row
    const int lq = l >> 4;        // quad id

    // ---------------- Phase A: geometry ----------------
    if (t < G) {
        const int e = e0 + t;
        float rx = r[e*3+0], ry = r[e*3+1], rz = r[e*3+2];
        float rad = sqrtf(rx*rx + ry*ry + rz*rz);
        s_rad[t]  = rad;
        s_mask[t] = (rad > 0.0f) ? 1 : 0;
        float inv = 1.0f / fmaxf(rad, 1e-12f);
        float x = rx*inv, y = ry*inv, z = rz*inv;

        const float SQ3  = 1.7320508075688772f;
        const float SQ15 = 3.872983346207417f;
        float Y10 = SQ3*y, Y11 = SQ3*z, Y12 = SQ3*x;
        s_Y1[t][0]=Y10; s_Y1[t][1]=Y11; s_Y1[t][2]=Y12;

        float Y20 = SQ15*x*y;
        float Y21 = SQ15*y*z;
        float Y22 = 1.118033988749895f*(3.f*z*z - 1.f);
        float Y23 = SQ15*z*x;
        float Y24 = 1.9364916731037085f*(x*x - y*y);

        const float n1  = 0.21650635094610965f;  // sqrt(3)/8
        const float r6  = 0.4082482904638631f;
        const float cA1 = n1 * r6;
        s_A1[t][0] = 0.0f;      s_A1[t][1] =  cA1*Y12; s_A1[t][2] = -cA1*Y11;
        s_A1[t][3] = -cA1*Y12;  s_A1[t][4] = 0.0f;     s_A1[t][5] =  cA1*Y10;
        s_A1[t][6] =  cA1*Y11;  s_A1[t][7] = -cA1*Y10; s_A1[t][8] = 0.0f;

        const float s2 = 0.7071067811865476f;
        float M00 = -r6*Y22 + s2*Y24;
        float M01 =  s2*Y20;
        float M02 =  s2*Y23;
        float M11 = -r6*Y22 - s2*Y24;
        float M12 =  s2*Y21;
        float M22 =  2.0f*r6*Y22;
        const float c5 = n1 * 0.4472135954999579f;
        s_A2[t][0] = c5*M11; s_A2[t][1] = c5*M12; s_A2[t][2] = c5*M01;
        s_A2[t][3] = c5*M12; s_A2[t][4] = c5*M22; s_A2[t][5] = c5*M02;
        s_A2[t][6] = c5*M01; s_A2[t][7] = c5*M02; s_A2[t][8] = c5*M00;
    }
    __syncthreads();

    // ---------------- Phase B: RBF ----------------
    for (int idx = t; idx < G*NB; idx += BLK) {
        int g = idx >> 6, k = idx & 63;
        float rad = s_rad[g];
        float c = (3.0f * (float)k) * (1.0f/63.0f);
        float d = (rad - c) * (64.0f/3.0f);
        s_basis[g][k] = __expf(-d*d);
    }
    __syncthreads();

    // ---------------- Phase C: h = silu(basis@W1+b1), fp32 ----------------
    for (int idx = t; idx < G*HID; idx += BLK) {
        int g = idx >> 7, c = idx & 127;
        float acc = b1[c];
#pragma unroll 8
        for (int k = 0; k < NB; ++k)
            acc = fmaf(s_basis[g][k], W1[k*HID + c], acc);
        float sig = 1.0f / (1.0f + __expf(-acc));
        s_h[g][c] = acc * sig;
    }
    __syncthreads();

    // ---------------- build A-fragments (hi/lo bf16), per lane ----------------
    // mfma_f32_16x16x32_bf16 A layout: lane holds A[m=lane&15][k = 8*(lane>>4)+j]
    bf16x8 ah[4], al[4];
    {
        const float* hrow = &s_h[lr][0];
#pragma unroll
        for (int kk = 0; kk < 4; ++kk) {
            f32x4 v0 = *reinterpret_cast<const f32x4*>(&hrow[kk*32 + lq*8]);
            f32x4 v1 = *reinterpret_cast<const f32x4*>(&hrow[kk*32 + lq*8 + 4]);
            float hv[8] = {v0.x, v0.y, v0.z, v0.w, v1.x, v1.y, v1.z, v1.w};
            bf16x8 h8, l8;
#pragma unroll
            for (int j = 0; j < 8; ++j) {
                unsigned short hb = f2bf(hv[j]);
                float rem = hv[j] - bf2f(hb);
                h8[j] = (short)hb;
                l8[j] = (short)f2bf(rem);
            }
            ah[kk] = h8; al[kk] = l8;
        }
    }

    // ---------------- Phase D: per-wave path GEMM via MFMA ----------------
    const float c00 = 0.17677669529663687f;   // 1/sqrt(32)
    const float cTR = 0.10206207261596577f;   // c00/sqrt(3)
    const float cBL = 0.125f;
    const float cD  = 0.125f;

    {
        const int nbase = w * 256;
#pragma unroll 2
        for (int nt = 0; nt < 16; ++nt) {
            const int n = nbase + nt*16 + lr;
            const bf16x8* bhp = reinterpret_cast<const bf16x8*>(&w2hi[(size_t)n * 128 + lq*8]);
            const bf16x8* blp = reinterpret_cast<const bf16x8*>(&w2lo[(size_t)n * 128 + lq*8]);
            f32x4 hh = {0.f,0.f,0.f,0.f}, hl = {0.f,0.f,0.f,0.f}, lh = {0.f,0.f,0.f,0.f};
#pragma unroll
            for (int kk = 0; kk < 4; ++kk) {
                bf16x8 Bh = bhp[kk*4];   // +32 elements per kk
                bf16x8 Bl = blp[kk*4];
                hh = __builtin_amdgcn_mfma_f32_16x16x32_bf16(ah[kk], Bh, hh, 0, 0, 0);
                hl = __builtin_amdgcn_mfma_f32_16x16x32_bf16(ah[kk], Bl, hl, 0, 0, 0);
                lh = __builtin_amdgcn_mfma_f32_16x16x32_bf16(al[kk], Bh, lh, 0, 0, 0);
            }
            f32x4 acc = (hh + hl) + lh;
            const float b2v = b2[n];
            acc.x += b2v; acc.y += b2v; acc.z += b2v; acc.w += b2v;

            // D layout (m89-verified): lane holds D[row=(lane>>4)*4+rr][col=lane&15]
            if (w == 0) {            // path 0 -> TL: out[e][nt][lr]
#pragma unroll
                for (int rr = 0; rr < 4; ++rr) {
                    int e = lq*4 + rr;
                    float v = c00 * acc[rr];
                    __builtin_nontemporal_store(v, &out[(size_t)(e0+e)*4096 + nt*64 + lr]);
                }
            } else if (w == 1) {     // path 1 -> BL: out[e][16+3*nt+a][lr]
#pragma unroll
                for (int rr = 0; rr < 4; ++rr) {
                    int e = lq*4 + rr;
                    float base = cBL * acc[rr];
#pragma unroll
                    for (int a = 0; a < 3; ++a) {
                        float v = base * s_Y1[e][a];
                        __builtin_nontemporal_store(v, &out[(size_t)(e0+e)*4096 + (16 + nt*3 + a)*64 + lr]);
                    }
                }
            } else if (w == 2) {     // path 2 -> TR: out[e][nt][16+3*lr+b]
#pragma unroll
                for (int rr = 0; rr < 4; ++rr) {
                    int e = lq*4 + rr;
                    float base = cTR * acc[rr];
#pragma unroll
                    for (int b = 0; b < 3; ++b) {
                        float v = base * s_Y1[e][b];
                        __builtin_nontemporal_store(v, &out[(size_t)(e0+e)*4096 + nt*64 + 16 + lr*3 + b]);
                    }
                }
            } else {                 // paths 3,4,5 -> LDS for BR assembly
                const int p = w - 3;
#pragma unroll
                for (int rr = 0; rr < 4; ++rr) {
                    int e = lq*4 + rr;
                    s_rv[p][e][nt*16 + lr] = acc[rr];
                }
            }
        }
    }
    __syncthreads();

    // ---------------- Phase E: bottom-right quadrant (paths 3+4+5) ----------------
    // items: 16 edges x 48 rows x 12 float4 = 9216
    for (int idx = t; idx < 16*48*12; idx += BLK) {
        int e     = idx / 576;
        int rem   = idx - e*576;
        int row16 = rem / 12;
        int cq    = rem - row16*12;
        int o = row16 / 3, a = row16 - o*3;
        int col16 = cq * 4;
        const float* rv3 = &s_rv[0][e][o*16];
        const float* rv4 = &s_rv[1][e][o*16];
        const float* rv5 = &s_rv[2][e][o*16];
        const float* A1 = &s_A1[e][a*3];
        const float* A2 = &s_A2[e][a*3];
        float v[4];
#pragma unroll
        for (int j = 0; j < 4; ++j) {
            int cc = col16 + j;
            int i = cc / 3, b = cc - i*3;
            float val = rv4[i]*A1[b] + rv5[i]*A2[b];
            if (a == b) val = fmaf(rv3[i], cD, val);
            v[j] = val;
        }
        f32x4 pack = {v[0], v[1], v[2], v[3]};
        __builtin_nontemporal_store(pack,
            reinterpret_cast<f32x4*>(&out[(size_t)(e0+e)*4096 + (16+row16)*64 + 16 + col16]));
    }

    // ---------------- fixup: masked edges get kernel2 ----------------
    bool any = false;
#pragma unroll
    for (int e = 0; e < G; ++e) any |= (s_mask[e] == 0);
    if (any) {
        __syncthreads();
        for (int idx = t; idx < G*1024; idx += BLK) {
            int e = idx >> 10;
            if (s_mask[e]) continue;
            int q = idx & 1023;
            int row = q >> 4, col = (q & 15) * 4;
            float v[4];
#pragma unroll
            for (int j = 0; j < 4; ++j) {
                int cl = col + j;
                float val = 0.0f;
                if (row < 16 && cl < 16) {
                    val = wl0[row*16 + cl] * 0.25f;
                } else if (row >= 16 && cl >= 16) {
                    int o = (row-16)/3, aa = (row-16)%3;
                    int i = (cl-16)/3,  bb = (cl-16)%3;
                    val = (aa == bb) ? wl1[o*16 + i] * 0.25f : 0.0f;
                }
                v[j] = val;
            }
            f32x4 pack = {v[0], v[1], v[2], v[3]};
            __builtin_nontemporal_store(pack,
                reinterpret_cast<f32x4*>(&out[(size_t)(e0+e)*4096 + row*64 + col]));
        }
    }
}

extern "C" void kernel_launch(void* const* d_in, const int* in_sizes, int n_in,
                              void* d_out, int out_size, void* d_ws, size_t ws_size,
                              hipStream_t stream) {
    const float* r   = (const float*)d_in[0];
    const float* W1  = (const float*)d_in[1];
    const float* b1  = (const float*)d_in[2];
    const float* W2  = (const float*)d_in[3];
    const float* b2  = (const float*)d_in[4];
    const float* wl0 = (const float*)d_in[5];
    const float* wl1 = (const float*)d_in[6];
    float* out = (float*)d_out;

    unsigned short* w2hi = (unsigned short*)d_ws;                 // 1536*128 bf16
    unsigned short* w2lo = w2hi + (size_t)MULD * HID;             // 1536*128 bf16

    prep_w2<<<MULD/32, 256, 0, stream>>>(W2, w2hi, w2lo);

    const int nblocks = E_TOTAL / G;   // 1250
    fused_tp_kernel<<<nblocks, BLK, 0, stream>>>(r, W1, b1, w2hi, w2lo, b2, wl0, wl1, out);
}

// Round 4
// 157.003 us; speedup vs baseline: 1.7371x; 1.4058x over previous
//
#include <hip/hip_runtime.h>
#include <math.h>

#define E_TOTAL 20000
#define G 16           // edges per block
#define BLK 512        // 8 waves
#define NB 64
#define HID 128
#define MULD 1536

typedef float f32x4 __attribute__((ext_vector_type(4)));
typedef short bf16x8 __attribute__((ext_vector_type(8)));

static __device__ __forceinline__ unsigned short f2bf(float f) {
    unsigned int u = __float_as_uint(f);
    unsigned int r = u + 0x7FFFu + ((u >> 16) & 1u);
    return (unsigned short)(r >> 16);
}
static __device__ __forceinline__ float bf2f(unsigned short h) {
    return __uint_as_float(((unsigned int)h) << 16);
}

// ---------------- prep: W2 [128][1536] fp32 -> W2t hi/lo [1536][128] bf16 ----------------
__global__ __launch_bounds__(256) void prep_w2(const float* __restrict__ W2,
                                               unsigned short* __restrict__ hi,
                                               unsigned short* __restrict__ lo) {
    __shared__ float s[32][132];
    const int n0 = blockIdx.x * 32;
    const int t = threadIdx.x;
    for (int rep = 0; rep < 16; ++rep) {
        int idx = rep * 256 + t;         // 4096 = 128k x 32n
        int k = idx >> 5, c = idx & 31;
        s[c][k] = W2[k * MULD + n0 + c];
    }
    __syncthreads();
    const int nl = t >> 3, kq = t & 7;
    unsigned short hb[16], lb[16];
#pragma unroll
    for (int j = 0; j < 16; ++j) {
        float f = s[nl][kq * 16 + j];
        unsigned short h = f2bf(f);
        float rem = f - bf2f(h);
        hb[j] = h;
        lb[j] = f2bf(rem);
    }
    const size_t base = (size_t)(n0 + nl) * 128 + kq * 16;
    *reinterpret_cast<uint4*>(&hi[base])     = *reinterpret_cast<uint4*>(&hb[0]);
    *reinterpret_cast<uint4*>(&hi[base + 8]) = *reinterpret_cast<uint4*>(&hb[8]);
    *reinterpret_cast<uint4*>(&lo[base])     = *reinterpret_cast<uint4*>(&lb[0]);
    *reinterpret_cast<uint4*>(&lo[base + 8]) = *reinterpret_cast<uint4*>(&lb[8]);
}

// ---------------- main fused kernel ----------------
__global__ __launch_bounds__(BLK) void fused_tp_kernel(
    const float* __restrict__ r,
    const float* __restrict__ W1,
    const float* __restrict__ b1,
    const unsigned short* __restrict__ w2hi,  // [1536][128] bf16 hi
    const unsigned short* __restrict__ w2lo,  // [1536][128] bf16 lo
    const float* __restrict__ b2,
    const float* __restrict__ wl0,
    const float* __restrict__ wl1,
    float* __restrict__ out)
{
    __shared__ __align__(16) float s_h[G][132];     // h fp32, padded
    __shared__ __align__(16) float s_basis[G][NB];
    __shared__ float s_Y1[G][3];
    __shared__ float s_A1[G][9];
    __shared__ float s_A2[G][9];
    __shared__ float s_rad[G];
    __shared__ int   s_mask[G];

    const int t  = threadIdx.x;
    const int e0 = blockIdx.x * G;
    const int w  = t >> 6;        // wave id 0..7
    const int l  = t & 63;
    const int lr = l & 15;        // edge row within tile (A) / n-col (D col)
    const int lq = l >> 4;        // quad id

    // ---------------- Phase A: geometry ----------------
    if (t < G) {
        const int e = e0 + t;
        float rx = r[e*3+0], ry = r[e*3+1], rz = r[e*3+2];
        float rad = sqrtf(rx*rx + ry*ry + rz*rz);
        s_rad[t]  = rad;
        s_mask[t] = (rad > 0.0f) ? 1 : 0;
        float inv = 1.0f / fmaxf(rad, 1e-12f);
        float x = rx*inv, y = ry*inv, z = rz*inv;

        const float SQ3  = 1.7320508075688772f;
        const float SQ15 = 3.872983346207417f;
        float Y10 = SQ3*y, Y11 = SQ3*z, Y12 = SQ3*x;
        s_Y1[t][0]=Y10; s_Y1[t][1]=Y11; s_Y1[t][2]=Y12;

        float Y20 = SQ15*x*y;
        float Y21 = SQ15*y*z;
        float Y22 = 1.118033988749895f*(3.f*z*z - 1.f);
        float Y23 = SQ15*z*x;
        float Y24 = 1.9364916731037085f*(x*x - y*y);

        const float n1  = 0.21650635094610965f;  // sqrt(3)/8
        const float r6  = 0.4082482904638631f;
        const float cA1 = n1 * r6;
        s_A1[t][0] = 0.0f;      s_A1[t][1] =  cA1*Y12; s_A1[t][2] = -cA1*Y11;
        s_A1[t][3] = -cA1*Y12;  s_A1[t][4] = 0.0f;     s_A1[t][5] =  cA1*Y10;
        s_A1[t][6] =  cA1*Y11;  s_A1[t][7] = -cA1*Y10; s_A1[t][8] = 0.0f;

        const float s2 = 0.7071067811865476f;
        float M00 = -r6*Y22 + s2*Y24;
        float M01 =  s2*Y20;
        float M02 =  s2*Y23;
        float M11 = -r6*Y22 - s2*Y24;
        float M12 =  s2*Y21;
        float M22 =  2.0f*r6*Y22;
        const float c5 = n1 * 0.4472135954999579f;
        s_A2[t][0] = c5*M11; s_A2[t][1] = c5*M12; s_A2[t][2] = c5*M01;
        s_A2[t][3] = c5*M12; s_A2[t][4] = c5*M22; s_A2[t][5] = c5*M02;
        s_A2[t][6] = c5*M01; s_A2[t][7] = c5*M02; s_A2[t][8] = c5*M00;
    }
    __syncthreads();

    // ---------------- Phase B: RBF ----------------
    for (int idx = t; idx < G*NB; idx += BLK) {
        int g = idx >> 6, k = idx & 63;
        float rad = s_rad[g];
        float c = (3.0f * (float)k) * (1.0f/63.0f);
        float d = (rad - c) * (64.0f/3.0f);
        s_basis[g][k] = __expf(-d*d);
    }
    __syncthreads();

    // ---------------- Phase C: h = silu(basis@W1+b1), f32x4 per thread ----------------
    {
        const int g  = t >> 5;          // 16 edges
        const int c0 = (t & 31) * 4;    // 128 cols / 4
        f32x4 acc = *reinterpret_cast<const f32x4*>(&b1[c0]);
#pragma unroll 8
        for (int k = 0; k < NB; ++k) {
            const f32x4 wv = *reinterpret_cast<const f32x4*>(&W1[k*HID + c0]);
            const float bv = s_basis[g][k];
            acc.x = fmaf(bv, wv.x, acc.x);
            acc.y = fmaf(bv, wv.y, acc.y);
            acc.z = fmaf(bv, wv.z, acc.z);
            acc.w = fmaf(bv, wv.w, acc.w);
        }
        f32x4 res;
        res.x = acc.x / (1.0f + __expf(-acc.x));
        res.y = acc.y / (1.0f + __expf(-acc.y));
        res.z = acc.z / (1.0f + __expf(-acc.z));
        res.w = acc.w / (1.0f + __expf(-acc.w));
        *reinterpret_cast<f32x4*>(&s_h[g][c0]) = res;
    }
    __syncthreads();

    // ---------------- A-fragments (hi/lo bf16) ----------------
    // A layout: lane holds A[m=lane&15(edge)][k = 8*(lane>>4) + 32*kk + j]
    bf16x8 ah[4], al[4];
    {
        const float* hrow = &s_h[lr][0];
#pragma unroll
        for (int kk = 0; kk < 4; ++kk) {
            f32x4 v0 = *reinterpret_cast<const f32x4*>(&hrow[kk*32 + lq*8]);
            f32x4 v1 = *reinterpret_cast<const f32x4*>(&hrow[kk*32 + lq*8 + 4]);
            float hv[8] = {v0.x, v0.y, v0.z, v0.w, v1.x, v1.y, v1.z, v1.w};
            bf16x8 h8, l8;
#pragma unroll
            for (int j = 0; j < 8; ++j) {
                unsigned short hb = f2bf(hv[j]);
                float rem = hv[j] - bf2f(hb);
                h8[j] = (short)hb;
                l8[j] = (short)f2bf(rem);
            }
            ah[kk] = h8; al[kk] = l8;
        }
    }

    const float c00 = 0.17677669529663687f;   // 1/sqrt(32)
    const float cTR = 0.10206207261596577f;   // c00/sqrt(3)
    const float cBL = 0.125f;
    const float cD  = 0.125f;

    // tile GEMM helper (macro-ish lambda): n-tile index nt_global in [0,96)
    auto tile_gemm = [&](int ntg) -> f32x4 {
        const int n = ntg*16 + lr;
        const bf16x8* bhp = reinterpret_cast<const bf16x8*>(&w2hi[(size_t)n * 128 + lq*8]);
        const bf16x8* blp = reinterpret_cast<const bf16x8*>(&w2lo[(size_t)n * 128 + lq*8]);
        f32x4 hh = {0.f,0.f,0.f,0.f}, hl = {0.f,0.f,0.f,0.f}, lh = {0.f,0.f,0.f,0.f};
#pragma unroll
        for (int kk = 0; kk < 4; ++kk) {
            bf16x8 Bh = bhp[kk*4];   // +32 bf16 per kk
            bf16x8 Bl = blp[kk*4];
            hh = __builtin_amdgcn_mfma_f32_16x16x32_bf16(ah[kk], Bh, hh, 0, 0, 0);
            hl = __builtin_amdgcn_mfma_f32_16x16x32_bf16(ah[kk], Bl, hl, 0, 0, 0);
            lh = __builtin_amdgcn_mfma_f32_16x16x32_bf16(al[kk], Bh, lh, 0, 0, 0);
        }
        f32x4 acc = (hh + hl) + lh;
        const float b2v = b2[n];
        acc.x += b2v; acc.y += b2v; acc.z += b2v; acc.w += b2v;
        return acc;
    };

    // ---------------- singles: paths 0,1,2 (2 tiles of each per wave) ----------------
#pragma unroll
    for (int s = 0; s < 6; ++s) {
        const int item = w + 8*s;        // 0..47, balanced: 2 per path per wave
        const int p  = item >> 4;
        const int nt = item & 15;
        f32x4 acc = tile_gemm(p*16 + nt);  // ntg = p*16+nt since path p tiles start at p*256

        if (p == 0) {
#pragma unroll
            for (int rr = 0; rr < 4; ++rr) {
                int e = lq*4 + rr;
                float v = c00 * acc[rr];
                __builtin_nontemporal_store(v, &out[(size_t)(e0+e)*4096 + nt*64 + lr]);
            }
        } else if (p == 1) {
#pragma unroll
            for (int rr = 0; rr < 4; ++rr) {
                int e = lq*4 + rr;
                float base = cBL * acc[rr];
#pragma unroll
                for (int a = 0; a < 3; ++a) {
                    float v = base * s_Y1[e][a];
                    __builtin_nontemporal_store(v, &out[(size_t)(e0+e)*4096 + (16 + nt*3 + a)*64 + lr]);
                }
            }
        } else {
#pragma unroll
            for (int rr = 0; rr < 4; ++rr) {
                int e = lq*4 + rr;
                float base = cTR * acc[rr];
#pragma unroll
                for (int b = 0; b < 3; ++b) {
                    float v = base * s_Y1[e][b];
                    __builtin_nontemporal_store(v, &out[(size_t)(e0+e)*4096 + nt*64 + 16 + lr*3 + b]);
                }
            }
        }
    }

    // ---------------- triples: BR quadrant, paths 3+4+5 at same o ----------------
#pragma unroll
    for (int tt = 0; tt < 2; ++tt) {
        const int o = w + 8*tt;          // 0..15
        f32x4 a3 = tile_gemm(48 + o);    // path 3 tiles start at ntg 48
        f32x4 a4 = tile_gemm(64 + o);
        f32x4 a5 = tile_gemm(80 + o);
#pragma unroll
        for (int rr = 0; rr < 4; ++rr) {
            int e = lq*4 + rr;
            const float* A1 = &s_A1[e][0];
            const float* A2 = &s_A2[e][0];
            float rv3 = cD * a3[rr], rv4 = a4[rr], rv5 = a5[rr];
            float* orow = &out[(size_t)(e0+e)*4096 + (16 + o*3)*64 + 16 + lr*3];
#pragma unroll
            for (int a = 0; a < 3; ++a) {
#pragma unroll
                for (int b = 0; b < 3; ++b) {
                    float v = fmaf(rv4, A1[a*3+b], rv5 * A2[a*3+b]);
                    if (a == b) v += rv3;
                    __builtin_nontemporal_store(v, &orow[a*64 + b]);
                }
            }
        }
    }

    // ---------------- fixup: masked edges get kernel2 ----------------
    bool any = false;
#pragma unroll
    for (int e = 0; e < G; ++e) any |= (s_mask[e] == 0);
    if (any) {
        __syncthreads();
        for (int idx = t; idx < G*1024; idx += BLK) {
            int e = idx >> 10;
            if (s_mask[e]) continue;
            int q = idx & 1023;
            int row = q >> 4, col = (q & 15) * 4;
            float v[4];
#pragma unroll
            for (int j = 0; j < 4; ++j) {
                int cl = col + j;
                float val = 0.0f;
                if (row < 16 && cl < 16) {
                    val = wl0[row*16 + cl] * 0.25f;
                } else if (row >= 16 && cl >= 16) {
                    int o = (row-16)/3, aa = (row-16)%3;
                    int i = (cl-16)/3,  bb = (cl-16)%3;
                    val = (aa == bb) ? wl1[o*16 + i] * 0.25f : 0.0f;
                }
                v[j] = val;
            }
            f32x4 pack = {v[0], v[1], v[2], v[3]};
            __builtin_nontemporal_store(pack,
                reinterpret_cast<f32x4*>(&out[(size_t)(e0+e)*4096 + row*64 + col]));
        }
    }
}

extern "C" void kernel_launch(void* const* d_in, const int* in_sizes, int n_in,
                              void* d_out, int out_size, void* d_ws, size_t ws_size,
                              hipStream_t stream) {
    const float* r   = (const float*)d_in[0];
    const float* W1  = (const float*)d_in[1];
    const float* b1  = (const float*)d_in[2];
    const float* W2  = (const float*)d_in[3];
    const float* b2  = (const float*)d_in[4];
    const float* wl0 = (const float*)d_in[5];
    const float* wl1 = (const float*)d_in[6];
    float* out = (float*)d_out;

    unsigned short* w2hi = (unsigned short*)d_ws;                 // 1536*128 bf16
    unsigned short* w2lo = w2hi + (size_t)MULD * HID;             // 1536*128 bf16

    prep_w2<<<MULD/32, 256, 0, stream>>>(W2, w2hi, w2lo);

    const int nblocks = E_TOTAL / G;   // 1250
    fused_tp_kernel<<<nblocks, BLK, 0, stream>>>(r, W1, b1, w2hi, w2lo, b2, wl0, wl1, out);
}

// Round 8
// 126.810 us; speedup vs baseline: 2.1507x; 1.2381x over previous
//
#include <hip/hip_runtime.h>
#include <math.h>

#define E_TOTAL 20000
#define G 32           // edges per block (2 MFMA edge-groups)
#define BLK 512        // 8 waves
#define NB 64
#define HID 128
#define MULD 1536

typedef float f32x4 __attribute__((ext_vector_type(4)));
typedef short bf16x8 __attribute__((ext_vector_type(8)));

static __device__ __forceinline__ unsigned short f2bf(float f) {
    unsigned int u = __float_as_uint(f);
    unsigned int r = u + 0x7FFFu + ((u >> 16) & 1u);
    return (unsigned short)(r >> 16);
}
static __device__ __forceinline__ float bf2f(unsigned short h) {
    return __uint_as_float(((unsigned int)h) << 16);
}

// ---------------- prep: W2 [128][1536] fp32 -> swizzled hi/lo bf16 ----------------
// slot layout: flat index i = ((ntg*4 + kk)*64 + lane)*8 + j
// content: W2t[n = ntg*16 + (lane&15)][k = kk*32 + (lane>>4)*8 + j] = W2[k][n]
// This is element-identical to what each lane consumed in the proven R4 kernel,
// but stored so a wave's load instruction is 1KB fully contiguous.
__global__ __launch_bounds__(256) void prep_w2s(const float* __restrict__ W2,
                                                unsigned short* __restrict__ hi,
                                                unsigned short* __restrict__ lo) {
    const int i = blockIdx.x * 256 + threadIdx.x;   // 0 .. 196607
    const int j    = i & 7;
    const int lane = (i >> 3) & 63;
    const int kk   = (i >> 9) & 3;
    const int ntg  = i >> 11;                        // 0..95
    const int k = kk*32 + (lane >> 4)*8 + j;
    const int n = ntg*16 + (lane & 15);
    const float f = W2[k * MULD + n];
    const unsigned short h = f2bf(f);
    hi[i] = h;
    lo[i] = f2bf(f - bf2f(h));
}

// ---------------- main fused kernel ----------------
__global__ __launch_bounds__(BLK) void fused_tp_kernel(
    const float* __restrict__ r,
    const float* __restrict__ W1,
    const float* __restrict__ b1,
    const unsigned short* __restrict__ w2hs,  // swizzled hi
    const unsigned short* __restrict__ w2ls,  // swizzled lo
    const float* __restrict__ b2,
    const float* __restrict__ wl0,
    const float* __restrict__ wl1,
    float* __restrict__ out)
{
    __shared__ __align__(16) float s_h[G][132];     // h fp32, padded
    __shared__ __align__(16) float s_basis[G][NB];
    __shared__ float s_Y1[G][3];
    __shared__ float s_A1[G][9];
    __shared__ float s_A2[G][9];
    __shared__ float s_rad[G];
    __shared__ int   s_mask[G];

    const int t  = threadIdx.x;
    const int e0 = blockIdx.x * G;
    const int w  = t >> 6;        // wave id 0..7
    const int l  = t & 63;
    const int lr = l & 15;
    const int lq = l >> 4;

    // ---------------- Phase A: geometry ----------------
    if (t < G) {
        const int e = e0 + t;
        float rx = r[e*3+0], ry = r[e*3+1], rz = r[e*3+2];
        float rad = sqrtf(rx*rx + ry*ry + rz*rz);
        s_rad[t]  = rad;
        s_mask[t] = (rad > 0.0f) ? 1 : 0;
        float inv = 1.0f / fmaxf(rad, 1e-12f);
        float x = rx*inv, y = ry*inv, z = rz*inv;

        const float SQ3  = 1.7320508075688772f;
        const float SQ15 = 3.872983346207417f;
        float Y10 = SQ3*y, Y11 = SQ3*z, Y12 = SQ3*x;
        s_Y1[t][0]=Y10; s_Y1[t][1]=Y11; s_Y1[t][2]=Y12;

        float Y20 = SQ15*x*y;
        float Y21 = SQ15*y*z;
        float Y22 = 1.118033988749895f*(3.f*z*z - 1.f);
        float Y23 = SQ15*z*x;
        float Y24 = 1.9364916731037085f*(x*x - y*y);

        const float n1  = 0.21650635094610965f;  // sqrt(3)/8
        const float r6  = 0.4082482904638631f;
        const float cA1 = n1 * r6;
        s_A1[t][0] = 0.0f;      s_A1[t][1] =  cA1*Y12; s_A1[t][2] = -cA1*Y11;
        s_A1[t][3] = -cA1*Y12;  s_A1[t][4] = 0.0f;     s_A1[t][5] =  cA1*Y10;
        s_A1[t][6] =  cA1*Y11;  s_A1[t][7] = -cA1*Y10; s_A1[t][8] = 0.0f;

        const float s2 = 0.7071067811865476f;
        float M00 = -r6*Y22 + s2*Y24;
        float M01 =  s2*Y20;
        float M02 =  s2*Y23;
        float M11 = -r6*Y22 - s2*Y24;
        float M12 =  s2*Y21;
        float M22 =  2.0f*r6*Y22;
        const float c5 = n1 * 0.4472135954999579f;
        s_A2[t][0] = c5*M11; s_A2[t][1] = c5*M12; s_A2[t][2] = c5*M01;
        s_A2[t][3] = c5*M12; s_A2[t][4] = c5*M22; s_A2[t][5] = c5*M02;
        s_A2[t][6] = c5*M01; s_A2[t][7] = c5*M02; s_A2[t][8] = c5*M00;
    }
    __syncthreads();

    // ---------------- Phase B: RBF ----------------
    for (int idx = t; idx < G*NB; idx += BLK) {
        int g = idx >> 6, k = idx & 63;
        float rad = s_rad[g];
        float c = (3.0f * (float)k) * (1.0f/63.0f);
        float d = (rad - c) * (64.0f/3.0f);
        s_basis[g][k] = __expf(-d*d);
    }
    __syncthreads();

    // ---------------- Phase C: h = silu(basis@W1+b1), f32x4 per item ----------------
    for (int idx = t; idx < G*32; idx += BLK) {      // 1024 f32x4 items
        const int g  = idx >> 5;
        const int c0 = (idx & 31) * 4;
        f32x4 acc = *reinterpret_cast<const f32x4*>(&b1[c0]);
#pragma unroll 8
        for (int k = 0; k < NB; ++k) {
            const f32x4 wv = *reinterpret_cast<const f32x4*>(&W1[k*HID + c0]);
            const float bv = s_basis[g][k];
            acc.x = fmaf(bv, wv.x, acc.x);
            acc.y = fmaf(bv, wv.y, acc.y);
            acc.z = fmaf(bv, wv.z, acc.z);
            acc.w = fmaf(bv, wv.w, acc.w);
        }
        f32x4 res;
        res.x = acc.x / (1.0f + __expf(-acc.x));
        res.y = acc.y / (1.0f + __expf(-acc.y));
        res.z = acc.z / (1.0f + __expf(-acc.z));
        res.w = acc.w / (1.0f + __expf(-acc.w));
        *reinterpret_cast<f32x4*>(&s_h[g][c0]) = res;
    }
    __syncthreads();

    // ---------------- A-fragments (hi/lo bf16), two edge groups ----------------
    // lane holds h[edge][k = 8lq + 32kk + j]; edge = eg*16 + lr
    bf16x8 ah0[4], al0[4], ah1[4], al1[4];
    {
        auto build = [&](const float* hrow, bf16x8* ah, bf16x8* al) {
#pragma unroll
            for (int kk = 0; kk < 4; ++kk) {
                f32x4 v0 = *reinterpret_cast<const f32x4*>(&hrow[kk*32 + lq*8]);
                f32x4 v1 = *reinterpret_cast<const f32x4*>(&hrow[kk*32 + lq*8 + 4]);
                float hv[8] = {v0.x, v0.y, v0.z, v0.w, v1.x, v1.y, v1.z, v1.w};
                bf16x8 h8, l8;
#pragma unroll
                for (int j = 0; j < 8; ++j) {
                    unsigned short hb = f2bf(hv[j]);
                    float rem = hv[j] - bf2f(hb);
                    h8[j] = (short)hb;
                    l8[j] = (short)f2bf(rem);
                }
                ah[kk] = h8; al[kk] = l8;
            }
        };
        build(&s_h[lr][0],      ah0, al0);
        build(&s_h[16 + lr][0], ah1, al1);
    }

    const float c00 = 0.17677669529663687f;   // 1/sqrt(32)
    const float cTR = 0.10206207261596577f;   // c00/sqrt(3)
    const float cBL = 0.125f;
    const float cD  = 0.125f;

    const bf16x8* ph = reinterpret_cast<const bf16x8*>(w2hs);
    const bf16x8* pl = reinterpret_cast<const bf16x8*>(w2ls);

    // Both edge-groups' GEMM for one n-tile; B loaded once (contiguous 1KB/instr).
    // Lane holds D[edge = eg*16 + 4lq+rr][n-in-tile = lr]  (proven R4 layout)
    auto tile_gemm2 = [&](int ntg, f32x4& r0, f32x4& r1) {
        f32x4 a_hh{0.f,0.f,0.f,0.f}, a_hl{0.f,0.f,0.f,0.f}, a_lh{0.f,0.f,0.f,0.f};
        f32x4 b_hh{0.f,0.f,0.f,0.f}, b_hl{0.f,0.f,0.f,0.f}, b_lh{0.f,0.f,0.f,0.f};
#pragma unroll
        for (int kk = 0; kk < 4; ++kk) {
            const bf16x8 Bh = ph[(ntg*4 + kk)*64 + l];
            const bf16x8 Bl = pl[(ntg*4 + kk)*64 + l];
            a_hh = __builtin_amdgcn_mfma_f32_16x16x32_bf16(ah0[kk], Bh, a_hh, 0, 0, 0);
            a_hl = __builtin_amdgcn_mfma_f32_16x16x32_bf16(ah0[kk], Bl, a_hl, 0, 0, 0);
            a_lh = __builtin_amdgcn_mfma_f32_16x16x32_bf16(al0[kk], Bh, a_lh, 0, 0, 0);
            b_hh = __builtin_amdgcn_mfma_f32_16x16x32_bf16(ah1[kk], Bh, b_hh, 0, 0, 0);
            b_hl = __builtin_amdgcn_mfma_f32_16x16x32_bf16(ah1[kk], Bl, b_hl, 0, 0, 0);
            b_lh = __builtin_amdgcn_mfma_f32_16x16x32_bf16(al1[kk], Bh, b_lh, 0, 0, 0);
        }
        const float b2v = b2[ntg*16 + lr];
        r0 = (a_hh + a_hl) + a_lh;
        r1 = (b_hh + b_hl) + b_lh;
        r0.x += b2v; r0.y += b2v; r0.z += b2v; r0.w += b2v;
        r1.x += b2v; r1.y += b2v; r1.z += b2v; r1.w += b2v;
    };

    // proven R4 store bodies, edge = eg*16 + 4lq + rr
    auto store_single = [&](f32x4 acc, int p, int nt, int eg) {
        if (p == 0) {
#pragma unroll
            for (int rr = 0; rr < 4; ++rr) {
                int e = eg*16 + lq*4 + rr;
                float v = c00 * acc[rr];
                __builtin_nontemporal_store(v, &out[(size_t)(e0+e)*4096 + nt*64 + lr]);
            }
        } else if (p == 1) {
#pragma unroll
            for (int rr = 0; rr < 4; ++rr) {
                int e = eg*16 + lq*4 + rr;
                float base = cBL * acc[rr];
#pragma unroll
                for (int a = 0; a < 3; ++a) {
                    float v = base * s_Y1[e][a];
                    __builtin_nontemporal_store(v, &out[(size_t)(e0+e)*4096 + (16 + nt*3 + a)*64 + lr]);
                }
            }
        } else {
#pragma unroll
            for (int rr = 0; rr < 4; ++rr) {
                int e = eg*16 + lq*4 + rr;
                float base = cTR * acc[rr];
#pragma unroll
                for (int b = 0; b < 3; ++b) {
                    float v = base * s_Y1[e][b];
                    __builtin_nontemporal_store(v, &out[(size_t)(e0+e)*4096 + nt*64 + 16 + lr*3 + b]);
                }
            }
        }
    };

    auto store_triple = [&](f32x4 a3, f32x4 a4, f32x4 a5, int o, int eg) {
#pragma unroll
        for (int rr = 0; rr < 4; ++rr) {
            int e = eg*16 + lq*4 + rr;
            const float* A1 = &s_A1[e][0];
            const float* A2 = &s_A2[e][0];
            float rv3 = cD * a3[rr], rv4 = a4[rr], rv5 = a5[rr];
            float* orow = &out[(size_t)(e0+e)*4096 + (16 + o*3)*64 + 16 + lr*3];
#pragma unroll
            for (int a = 0; a < 3; ++a) {
#pragma unroll
                for (int b = 0; b < 3; ++b) {
                    float v = fmaf(rv4, A1[a*3+b], rv5 * A2[a*3+b]);
                    if (a == b) v += rv3;
                    __builtin_nontemporal_store(v, &orow[a*64 + b]);
                }
            }
        }
    };

    // ---------------- singles: paths 0,1,2 (2 tiles of each per wave) ----------------
#pragma unroll
    for (int s = 0; s < 6; ++s) {
        const int item = w + 8*s;        // 0..47; ntg = item; p = item>>4; nt = item&15
        const int p  = item >> 4;
        const int nt = item & 15;
        f32x4 r0, r1;
        tile_gemm2(item, r0, r1);
        store_single(r0, p, nt, 0);
        store_single(r1, p, nt, 1);
    }

    // ---------------- triples: BR quadrant, paths 3+4+5 at same o ----------------
#pragma unroll
    for (int tt = 0; tt < 2; ++tt) {
        const int o = w + 8*tt;          // 0..15
        f32x4 a3_0, a3_1, a4_0, a4_1, a5_0, a5_1;
        tile_gemm2(48 + o, a3_0, a3_1);
        tile_gemm2(64 + o, a4_0, a4_1);
        tile_gemm2(80 + o, a5_0, a5_1);
        store_triple(a3_0, a4_0, a5_0, o, 0);
        store_triple(a3_1, a4_1, a5_1, o, 1);
    }

    // ---------------- fixup: masked edges get kernel2 ----------------
    bool any = false;
#pragma unroll
    for (int e = 0; e < G; ++e) any |= (s_mask[e] == 0);
    if (any) {
        __syncthreads();
        for (int idx = t; idx < G*1024; idx += BLK) {
            int e = idx >> 10;
            if (s_mask[e]) continue;
            int q = idx & 1023;
            int row = q >> 4, col = (q & 15) * 4;
            float v[4];
#pragma unroll
            for (int j = 0; j < 4; ++j) {
                int cl = col + j;
                float val = 0.0f;
                if (row < 16 && cl < 16) {
                    val = wl0[row*16 + cl] * 0.25f;
                } else if (row >= 16 && cl >= 16) {
                    int o = (row-16)/3, aa = (row-16)%3;
                    int i = (cl-16)/3,  bb = (cl-16)%3;
                    val = (aa == bb) ? wl1[o*16 + i] * 0.25f : 0.0f;
                }
                v[j] = val;
            }
            f32x4 pack = {v[0], v[1], v[2], v[3]};
            __builtin_nontemporal_store(pack,
                reinterpret_cast<f32x4*>(&out[(size_t)(e0+e)*4096 + row*64 + col]));
        }
    }
}

extern "C" void kernel_launch(void* const* d_in, const int* in_sizes, int n_in,
                              void* d_out, int out_size, void* d_ws, size_t ws_size,
                              hipStream_t stream) {
    const float* r   = (const float*)d_in[0];
    const float* W1  = (const float*)d_in[1];
    const float* b1  = (const float*)d_in[2];
    const float* W2  = (const float*)d_in[3];
    const float* b2  = (const float*)d_in[4];
    const float* wl0 = (const float*)d_in[5];
    const float* wl1 = (const float*)d_in[6];
    float* out = (float*)d_out;

    unsigned short* w2hs = (unsigned short*)d_ws;                 // 196608 bf16
    unsigned short* w2ls = w2hs + (size_t)MULD * HID;             // 196608 bf16

    prep_w2s<<<(MULD * HID) / 256, 256, 0, stream>>>(W2, w2hs, w2ls);

    const int nblocks = E_TOTAL / G;   // 625
    fused_tp_kernel<<<nblocks, BLK, 0, stream>>>(r, W1, b1, w2hs, w2ls, b2, wl0, wl1, out);
}